// Round 5
// baseline (72.657 us; speedup 1.0000x reference)
//
#include <hip/hip_runtime.h>

// Problem constants (from reference):
//   left/right: [2, 32, 64, 128] f32, MAXDISP=192 -> D=48 coarse disparities
//   output: [2, 256, 512] f32 (soft-argmin disparity map)
#define BB 2
#define CC 32
#define HC 64
#define WC 128
#define DC 48
#define HO 256
#define WO 512
#define MAXD 192

// ---------------------------------------------------------------------------
// Single fused kernel. Block = (output row r, 128-pixel column group g).
// Phase 1 : channel-sum the 4 needed coarse rows (L/R x h0/h1) with float4
//           global loads; LDS-combine quarters; fh-blend -> Lh[128], Rh[128].
// Phase 2 : 4-way dd split across waves (k = t>>7 wave-uniform), per-pixel
//           register v-window, fused d-upsample + softmax + soft-argmin.
// Phase 3 : LDS-combine the 4 partials, coalesced store.
// ---------------------------------------------------------------------------
template <int K>
__device__ inline void quarter_work(const float* __restrict__ Rh,
                                    int w0, int w1, float c0, float c1,
                                    float lw0, float lw1,
                                    float& plsum, float& pssum) {
    constexpr int DDLO = 48 * K;
    constexpr int DDHI = 48 * K + 47;
    constexpr int DLO  = (DDLO * (DC - 1)) / (MAXD - 1);   // floor
    constexpr int DHI  = (DDHI * (DC - 1)) / (MAXD - 1);
    constexpr int NV   = DHI - DLO + 2;                    // v[DLO .. DHI+1]

    float vv[NV];
#pragma unroll
    for (int j = 0; j < NV; ++j) {
        int d = DLO + j;
        if (d > DC - 1) { vv[j] = vv[j - 1]; continue; }   // clamp v[48]->v[47]
        int i0 = w0 - d; float m0 = (i0 >= 0) ? 1.f : 0.f; i0 = max(i0, 0);
        int i1 = w1 - d; float m1 = (i1 >= 0) ? 1.f : 0.f; i1 = max(i1, 0);
        vv[j] = m0 * c0 * (lw0 + Rh[i0]) + m1 * c1 * (lw1 + Rh[i1]);
    }
    // 2x2 independent accumulator chains so exp->fma chains overlap
    float ls0 = 0.f, ls1 = 0.f, ss0 = 0.f, ss1 = 0.f;
#pragma unroll
    for (int dd = DDLO; dd <= DDHI; ++dd) {
        int d    = (dd * (DC - 1)) / (MAXD - 1);           // compile-time fold
        float wd = (float)dd * (47.0f / 191.0f) - (float)d;
        float vc = vv[d - DLO];
        float x  = vc + wd * (vv[d - DLO + 1] - vc);
        float e  = __expf(x);                              // |x| small: no max shift
        if (dd & 1) { ls1 += e; ss1 += e * (float)dd; }
        else        { ls0 += e; ss0 += e * (float)dd; }
    }
    plsum = ls0 + ls1;
    pssum = ss0 + ss1;
}

__global__ __launch_bounds__(512) void fused_disparity_kernel(
    const float* __restrict__ left, const float* __restrict__ right,
    float* __restrict__ out) {
    __shared__ float sbuf[4][4][WC];   // [rowSel][chQuarter][w] channel partials
    __shared__ float Lh[WC];
    __shared__ float Rh[WC];
    __shared__ float redL[4][WC];
    __shared__ float redS[4][WC];

    int blk = blockIdx.x;            // [0, 2048)
    int r   = blk >> 2;              // output row [0, BB*HO)
    int g   = blk & 3;               // 128-pixel column group
    int b   = r >> 8;
    int hh  = r & (HO - 1);

    float src_h = (float)hh * (63.0f / 255.0f);
    int h0 = (int)src_h; if (h0 > HC - 1) h0 = HC - 1;
    int h1 = min(h0 + 1, HC - 1);
    float fh = src_h - (float)h0;

    int t = threadIdx.x;

    // ---- Phase 1: channel sums via float4 loads ----
    {
        int rsel = t >> 7;            // 0:L@h0 1:L@h1 2:R@h0 3:R@h1
        int rest = t & (WC - 1);
        int cq   = rest >> 5;         // channel quarter (8 channels)
        int q    = rest & 31;         // float4 column
        int hrow = (rsel & 1) ? h1 : h0;
        const float* src = ((rsel < 2) ? left : right)
                         + (size_t)b * (CC * HC * WC)
                         + (size_t)(cq * 8) * (HC * WC) + hrow * WC + q * 4;
        float4 acc = make_float4(0.f, 0.f, 0.f, 0.f);
#pragma unroll
        for (int i = 0; i < 8; ++i) {
            float4 v = *(const float4*)(src + (size_t)i * (HC * WC));
            acc.x += v.x; acc.y += v.y; acc.z += v.z; acc.w += v.w;
        }
        *(float4*)&sbuf[rsel][cq][q * 4] = acc;
    }
    __syncthreads();

    // ---- Phase 1b: combine quarters + fh blend ----
    if (t < WC) {
        float a0 = sbuf[0][0][t] + sbuf[0][1][t] + sbuf[0][2][t] + sbuf[0][3][t];
        float a1 = sbuf[1][0][t] + sbuf[1][1][t] + sbuf[1][2][t] + sbuf[1][3][t];
        Lh[t] = (1.f - fh) * a0 + fh * a1;
    } else if (t < 2 * WC) {
        int u = t - WC;
        float a0 = sbuf[2][0][u] + sbuf[2][1][u] + sbuf[2][2][u] + sbuf[2][3][u];
        float a1 = sbuf[3][0][u] + sbuf[3][1][u] + sbuf[3][2][u] + sbuf[3][3][u];
        Rh[u] = (1.f - fh) * a0 + fh * a1;
    }
    __syncthreads();

    // ---- Phase 2: per-pixel quarter of the dd range ----
    int p = t & (WC - 1);            // pixel within group
    int k = t >> 7;                  // dd quarter (wave-uniform)
    int ww = g * WC + p;

    float src_w = (float)ww * (127.0f / 511.0f);
    int w0 = (int)src_w; if (w0 > WC - 1) w0 = WC - 1;
    int w1 = min(w0 + 1, WC - 1);
    float fw = src_w - (float)w0;

    const float scale = 1.0f / 64.0f;    // mean over 2C = 64 channels
    float c0 = (1.f - fw) * scale;
    float c1 = fw * scale;
    float lw0 = Lh[w0];
    float lw1 = Lh[w1];

    float pls, pss;
    switch (k) {                      // wave-uniform branch, no divergence
        case 0: quarter_work<0>(Rh, w0, w1, c0, c1, lw0, lw1, pls, pss); break;
        case 1: quarter_work<1>(Rh, w0, w1, c0, c1, lw0, lw1, pls, pss); break;
        case 2: quarter_work<2>(Rh, w0, w1, c0, c1, lw0, lw1, pls, pss); break;
        default: quarter_work<3>(Rh, w0, w1, c0, c1, lw0, lw1, pls, pss); break;
    }
    redL[k][p] = pls;
    redS[k][p] = pss;
    __syncthreads();

    // ---- Phase 3: combine quarters, soft-argmin, coalesced store ----
    if (t < WC) {
        float ls = redL[0][t] + redL[1][t] + redL[2][t] + redL[3][t];
        float ss = redS[0][t] + redS[1][t] + redS[2][t] + redS[3][t];
        out[r * WO + g * WC + t] = ss / ls;
    }
}

extern "C" void kernel_launch(void* const* d_in, const int* in_sizes, int n_in,
                              void* d_out, int out_size, void* d_ws, size_t ws_size,
                              hipStream_t stream) {
    const float* left  = (const float*)d_in[0];
    const float* right = (const float*)d_in[1];
    float* out = (float*)d_out;
    (void)d_ws; (void)ws_size;

    fused_disparity_kernel<<<BB * HO * 4, 512, 0, stream>>>(left, right, out);
}

// Round 6
// 71.593 us; speedup vs baseline: 1.0149x; 1.0149x over previous
//
#include <hip/hip_runtime.h>

// Problem constants (from reference):
//   left/right: [2, 32, 64, 128] f32, MAXDISP=192 -> D=48 coarse disparities
//   output: [2, 256, 512] f32 (soft-argmin disparity map)
//
// Best measured variant (R3, 70.7 us). The timed duration is dominated by
// harness reset fills (268 MB d_ws re-poison at ~83% HBM peak ~= 41 us, plus
// input restores); the two kernels below account for only ~6-9 us and sit
// near their VALU/latency floor (~50M v_exp_f32 + FMA chains).
#define BB 2
#define CC 32
#define HC 64
#define WC 128
#define DC 48
#define HO 256
#define WO 512
#define MAXD 192

// ---------------------------------------------------------------------------
// Kernel A: channel sums -> Ls[b][h][w], Rs[b][h][w]  (each 2*64*128 f32)
// grid 256 blocks x 256 threads; block -> (mat, b, h); threads: sel=t>>7 sums
// 16 channels (coalesced over w), LDS-combine the two halves.
// ---------------------------------------------------------------------------
__global__ __launch_bounds__(256) void sum_channels_kernel(
    const float* __restrict__ left, const float* __restrict__ right,
    float* __restrict__ Ls, float* __restrict__ Rs) {
    __shared__ float sbuf[2][WC];
    int blk = blockIdx.x;            // [0,256)
    int m   = blk >> 7;              // 0 = left, 1 = right
    int b   = (blk >> 6) & 1;
    int h   = blk & (HC - 1);
    int t   = threadIdx.x;
    int sel = t >> 7;                // channel half
    int w   = t & (WC - 1);

    const float* src = (m ? right : left)
                     + (size_t)b * (CC * HC * WC)
                     + (size_t)(sel * 16) * (HC * WC) + h * WC + w;
    float s = 0.f;
#pragma unroll
    for (int c = 0; c < 16; ++c) s += src[c * (HC * WC)];
    sbuf[sel][w] = s;
    __syncthreads();
    if (t < WC) {
        float* dst = m ? Rs : Ls;
        dst[b * (HC * WC) + h * WC + t] = sbuf[0][t] + sbuf[1][t];
    }
}

// ---------------------------------------------------------------------------
// Kernel B: per output pixel, fused bilinear + cost-volume collapse +
// d-upsample + softmax + soft-argmin. dd range split 4-ways across waves.
// ---------------------------------------------------------------------------
template <int K>
__device__ inline void quarter_work(const float* __restrict__ Rh,
                                    int w0, int w1, float c0, float c1,
                                    float lw0, float lw1,
                                    float& plsum, float& pssum) {
    constexpr int DDLO = 48 * K;
    constexpr int DDHI = 48 * K + 47;
    constexpr int DLO  = (DDLO * (DC - 1)) / (MAXD - 1);   // floor
    constexpr int DHI  = (DDHI * (DC - 1)) / (MAXD - 1);
    constexpr int NV   = DHI - DLO + 2;                    // v[DLO .. DHI+1]

    float vv[NV];
#pragma unroll
    for (int j = 0; j < NV; ++j) {
        int d = DLO + j;
        if (d > DC - 1) { vv[j] = vv[j - 1]; continue; }   // clamp v[48]->v[47]
        int i0 = w0 - d; float m0 = (i0 >= 0) ? 1.f : 0.f; i0 = max(i0, 0);
        int i1 = w1 - d; float m1 = (i1 >= 0) ? 1.f : 0.f; i1 = max(i1, 0);
        vv[j] = m0 * c0 * (lw0 + Rh[i0]) + m1 * c1 * (lw1 + Rh[i1]);
    }
    // 2x2 independent accumulator chains so exp->fma chains overlap
    float ls0 = 0.f, ls1 = 0.f, ss0 = 0.f, ss1 = 0.f;
#pragma unroll
    for (int dd = DDLO; dd <= DDHI; ++dd) {
        int d    = (dd * (DC - 1)) / (MAXD - 1);           // compile-time fold
        float wd = (float)dd * (47.0f / 191.0f) - (float)d;
        float vc = vv[d - DLO];
        float x  = vc + wd * (vv[d - DLO + 1] - vc);
        float e  = __expf(x);                              // |x| small: no max shift
        if (dd & 1) { ls1 += e; ss1 += e * (float)dd; }
        else        { ls0 += e; ss0 += e * (float)dd; }
    }
    plsum = ls0 + ls1;
    pssum = ss0 + ss1;
}

__global__ __launch_bounds__(512) void disparity_kernel(
    const float* __restrict__ Ls, const float* __restrict__ Rs,
    float* __restrict__ out) {
    __shared__ float Lh[WC];
    __shared__ float Rh[WC];
    __shared__ float redL[4][WC];
    __shared__ float redS[4][WC];

    int blk = blockIdx.x;            // [0, 2048)
    int r   = blk >> 2;              // output row [0, BB*HO)
    int g   = blk & 3;               // column group
    int b   = r >> 8;
    int hh  = r & (HO - 1);

    float src_h = (float)hh * (63.0f / 255.0f);
    int h0 = (int)src_h; if (h0 > HC - 1) h0 = HC - 1;
    int h1 = min(h0 + 1, HC - 1);
    float fh = src_h - (float)h0;

    int t = threadIdx.x;

    // Phase 1: load + fh-blend the two coarse rows (L2-resident, coalesced)
    if (t < WC) {
        const float* p = Ls + b * (HC * WC) + t;
        Lh[t] = (1.f - fh) * p[h0 * WC] + fh * p[h1 * WC];
    } else if (t < 2 * WC) {
        int u = t - WC;
        const float* p = Rs + b * (HC * WC) + u;
        Rh[u] = (1.f - fh) * p[h0 * WC] + fh * p[h1 * WC];
    }
    __syncthreads();

    // Phase 2: per-pixel quarter work. k = t>>7 is wave-uniform (waves 2k,2k+1).
    int p = t & (WC - 1);            // pixel within group
    int k = t >> 7;                  // dd quarter
    int ww = g * WC + p;

    float src_w = (float)ww * (127.0f / 511.0f);
    int w0 = (int)src_w; if (w0 > WC - 1) w0 = WC - 1;
    int w1 = min(w0 + 1, WC - 1);
    float fw = src_w - (float)w0;

    const float scale = 1.0f / 64.0f;    // mean over 2C = 64 channels
    float c0 = (1.f - fw) * scale;
    float c1 = fw * scale;
    float lw0 = Lh[w0];
    float lw1 = Lh[w1];

    float pls, pss;
    switch (k) {                      // wave-uniform branch, no divergence
        case 0: quarter_work<0>(Rh, w0, w1, c0, c1, lw0, lw1, pls, pss); break;
        case 1: quarter_work<1>(Rh, w0, w1, c0, c1, lw0, lw1, pls, pss); break;
        case 2: quarter_work<2>(Rh, w0, w1, c0, c1, lw0, lw1, pls, pss); break;
        default: quarter_work<3>(Rh, w0, w1, c0, c1, lw0, lw1, pls, pss); break;
    }
    redL[k][p] = pls;
    redS[k][p] = pss;
    __syncthreads();

    // Phase 3: combine quarters, soft-argmin, coalesced store
    if (t < WC) {
        float ls = redL[0][t] + redL[1][t] + redL[2][t] + redL[3][t];
        float ss = redS[0][t] + redS[1][t] + redS[2][t] + redS[3][t];
        out[r * WO + g * WC + t] = ss / ls;
    }
}

extern "C" void kernel_launch(void* const* d_in, const int* in_sizes, int n_in,
                              void* d_out, int out_size, void* d_ws, size_t ws_size,
                              hipStream_t stream) {
    const float* left  = (const float*)d_in[0];
    const float* right = (const float*)d_in[1];
    float* out = (float*)d_out;
    float* Ls  = (float*)d_ws;                 // BB*HC*WC floats
    float* Rs  = Ls + BB * HC * WC;            // BB*HC*WC floats

    sum_channels_kernel<<<256, 256, 0, stream>>>(left, right, Ls, Rs);
    disparity_kernel<<<BB * HO * 4, 512, 0, stream>>>(Ls, Rs, out);
}